// Round 5
// baseline (94.175 us; speedup 1.0000x reference)
//
#include <hip/hip_runtime.h>

// Problem constants (from reference)
#define BATCH   4
#define N_VERTS 10000
#define N_FACES 20000
#define CUT_NUM 8
#define N_SAMP  80000
#define CC      128

typedef float f32x4 __attribute__((ext_vector_type(4)));
typedef int   i32x4 __attribute__((ext_vector_type(4)));

// ---------------------------------------------------------------------------
// Stage 1: resolve the batch-independent index chain once per (v,k).
//   quad[e] = { F[I[s]][0], F[I[s]][1], F[I[s]][2], s }  where s = xg[e]
// 80000 entries, 16B each, written coalesced into d_ws (1.28 MB).
// ---------------------------------------------------------------------------
__global__ __launch_bounds__(256) void idx_prep(
    const int* __restrict__ xg,   // [N_VERTS*CUT_NUM]
    const int* __restrict__ Fc,   // [N_FACES][3]
    const int* __restrict__ Iv,   // [N_SAMP]
    i32x4*     __restrict__ quad) // [N_VERTS*CUT_NUM]
{
    const int e = blockIdx.x * 256 + threadIdx.x;
    if (e >= N_VERTS * CUT_NUM) return;
    const int s   = xg[e];
    const int fid = Iv[s];
    i32x4 q;
    q.x = Fc[fid * 3 + 0];
    q.y = Fc[fid * 3 + 1];
    q.z = Fc[fid * 3 + 2];
    q.w = s;
    quad[e] = q;
}

// ---------------------------------------------------------------------------
// Stage 2: one block per vertex; 8 k-groups of 32 lanes; batch loop inside
// (indices are batch-independent -> 4x ILP, 4x fewer index loads).
// out[b][v][k][c] = w0*x[b][v0][c] + w1*x[b][v1][c] + w2*x[b][v2][c] - x[b][v][c]
// ---------------------------------------------------------------------------
__global__ __launch_bounds__(256) void disk_features_main(
    const float* __restrict__ xf,   // [BATCH][N_VERTS][CC]
    const float* __restrict__ Bw,   // [BATCH][N_SAMP][3]
    const i32x4* __restrict__ quad, // [N_VERTS*CUT_NUM]
    float*       __restrict__ out)  // [BATCH][N_VERTS][CUT_NUM][CC]
{
    const int v    = blockIdx.x;
    const int t    = threadIdx.x;
    const int k    = t >> 5;        // 0..7
    const int lane = t & 31;        // 0..31
    const int c0   = lane * 4;

    const i32x4 q = quad[v * CUT_NUM + k];   // broadcast within the 32-lane group
    const size_t o0 = (size_t)q.x * CC + c0;
    const size_t o1 = (size_t)q.y * CC + c0;
    const size_t o2 = (size_t)q.z * CC + c0;
    const size_t ox = (size_t)v   * CC + c0;

    #pragma unroll
    for (int b = 0; b < BATCH; ++b) {
        const float* bw = Bw + ((size_t)b * N_SAMP + q.w) * 3;
        const float w0 = bw[0];
        const float w1 = bw[1];
        const float w2 = bw[2];

        const float* xb = xf + (size_t)b * N_VERTS * CC;
        const f32x4 f0 = *(const f32x4*)(xb + o0);
        const f32x4 f1 = *(const f32x4*)(xb + o1);
        const f32x4 f2 = *(const f32x4*)(xb + o2);
        const f32x4 fx = *(const f32x4*)(xb + ox);

        f32x4 r;
        r.x = fmaf(w0, f0.x, fmaf(w1, f1.x, fmaf(w2, f2.x, -fx.x)));
        r.y = fmaf(w0, f0.y, fmaf(w1, f1.y, fmaf(w2, f2.y, -fx.y)));
        r.z = fmaf(w0, f0.z, fmaf(w1, f1.z, fmaf(w2, f2.z, -fx.z)));
        r.w = fmaf(w0, f0.w, fmaf(w1, f1.w, fmaf(w2, f2.w, -fx.w)));

        f32x4* dst = (f32x4*)(out + ((((size_t)b * N_VERTS + v) * CUT_NUM + k) * CC + c0));
        __builtin_nontemporal_store(r, dst);
    }
}

// ---------------------------------------------------------------------------
// Fallback: original fused single kernel (used only if d_ws is too small).
// ---------------------------------------------------------------------------
__global__ __launch_bounds__(256) void fused_disk_features(
    const float* __restrict__ xf,
    const float* __restrict__ Bw,
    const int*   __restrict__ xg,
    const int*   __restrict__ Fc,
    const int*   __restrict__ Iv,
    float*       __restrict__ out)
{
    const int v    = blockIdx.x;
    const int b    = blockIdx.y;
    const int t    = threadIdx.x;
    const int k    = t >> 5;
    const int lane = t & 31;
    const int c0   = lane * 4;

    const int s   = xg[v * CUT_NUM + k];
    const int fid = Iv[s];
    const int v0  = Fc[fid * 3 + 0];
    const int v1  = Fc[fid * 3 + 1];
    const int v2  = Fc[fid * 3 + 2];

    const float* bw = Bw + ((size_t)b * N_SAMP + s) * 3;
    const float w0 = bw[0];
    const float w1 = bw[1];
    const float w2 = bw[2];

    const float* xb = xf + (size_t)b * N_VERTS * CC;
    const f32x4 f0 = *(const f32x4*)(xb + (size_t)v0 * CC + c0);
    const f32x4 f1 = *(const f32x4*)(xb + (size_t)v1 * CC + c0);
    const f32x4 f2 = *(const f32x4*)(xb + (size_t)v2 * CC + c0);
    const f32x4 fx = *(const f32x4*)(xb + (size_t)v  * CC + c0);

    f32x4 r;
    r.x = fmaf(w0, f0.x, fmaf(w1, f1.x, fmaf(w2, f2.x, -fx.x)));
    r.y = fmaf(w0, f0.y, fmaf(w1, f1.y, fmaf(w2, f2.y, -fx.y)));
    r.z = fmaf(w0, f0.z, fmaf(w1, f1.z, fmaf(w2, f2.z, -fx.z)));
    r.w = fmaf(w0, f0.w, fmaf(w1, f1.w, fmaf(w2, f2.w, -fx.w)));

    f32x4* dst = (f32x4*)(out + ((((size_t)b * N_VERTS + v) * CUT_NUM + k) * CC + c0));
    __builtin_nontemporal_store(r, dst);
}

extern "C" void kernel_launch(void* const* d_in, const int* in_sizes, int n_in,
                              void* d_out, int out_size, void* d_ws, size_t ws_size,
                              hipStream_t stream) {
    const float* xf = (const float*)d_in[0];   // x_features (4,10000,128)
    const float* Bw = (const float*)d_in[1];   // B          (4,80000,3)
    const int*   xg = (const int*)  d_in[2];   // x_graph    (10000,8)
    const int*   Fc = (const int*)  d_in[3];   // F          (20000,3)
    const int*   Iv = (const int*)  d_in[4];   // I          (80000,)
    float*       out = (float*)d_out;          // (4,10000,8,128)

    const size_t quad_bytes = (size_t)N_VERTS * CUT_NUM * sizeof(i32x4);
    if (ws_size >= quad_bytes) {
        i32x4* quad = (i32x4*)d_ws;
        const int n_e = N_VERTS * CUT_NUM;
        idx_prep<<<(n_e + 255) / 256, 256, 0, stream>>>(xg, Fc, Iv, quad);
        disk_features_main<<<N_VERTS, 256, 0, stream>>>(xf, Bw, quad, out);
    } else {
        dim3 grid(N_VERTS, BATCH);
        fused_disk_features<<<grid, 256, 0, stream>>>(xf, Bw, xg, Fc, Iv, out);
    }
}

// Round 6
// 65.750 us; speedup vs baseline: 1.4323x; 1.4323x over previous
//
#include <hip/hip_runtime.h>

// Problem constants (from reference)
#define BATCH   4
#define N_VERTS 10000
#define N_FACES 20000
#define CUT_NUM 8
#define N_SAMP  80000
#define CC      128

typedef float f32x4 __attribute__((ext_vector_type(4)));
typedef int   i32x4 __attribute__((ext_vector_type(4)));

// ---------------------------------------------------------------------------
// Stage 1: resolve the batch-independent index chain once per (v,k).
//   quad[e] = { F[I[s]][0], F[I[s]][1], F[I[s]][2], s }  where s = xg[e]
// 80000 entries, 16B each (1.28 MB in d_ws, L2-resident for stage 2).
// ---------------------------------------------------------------------------
__global__ __launch_bounds__(256) void idx_prep(
    const int* __restrict__ xg,   // [N_VERTS*CUT_NUM]
    const int* __restrict__ Fc,   // [N_FACES][3]
    const int* __restrict__ Iv,   // [N_SAMP]
    i32x4*     __restrict__ quad) // [N_VERTS*CUT_NUM]
{
    const int e = blockIdx.x * 256 + threadIdx.x;
    if (e >= N_VERTS * CUT_NUM) return;
    const int s   = xg[e];
    const int fid = Iv[s];
    i32x4 q;
    q.x = Fc[fid * 3 + 0];
    q.y = Fc[fid * 3 + 1];
    q.z = Fc[fid * 3 + 2];
    q.w = s;
    quad[e] = q;
}

// ---------------------------------------------------------------------------
// Stage 2: one block per (v,b) — same parallelism/locality as round 4's best.
// Dependent chain is now quad -> {weights, features} (2 levels, was 4).
// ---------------------------------------------------------------------------
__global__ __launch_bounds__(256) void disk_features_main(
    const float* __restrict__ xf,   // [BATCH][N_VERTS][CC]
    const float* __restrict__ Bw,   // [BATCH][N_SAMP][3]
    const i32x4* __restrict__ quad, // [N_VERTS*CUT_NUM]
    float*       __restrict__ out)  // [BATCH][N_VERTS][CUT_NUM][CC]
{
    const int v    = blockIdx.x;
    const int b    = blockIdx.y;
    const int t    = threadIdx.x;
    const int k    = t >> 5;        // 0..7
    const int lane = t & 31;        // 0..31
    const int c0   = lane * 4;

    const i32x4 q = quad[v * CUT_NUM + k];   // broadcast within 32-lane group

    const float* bw = Bw + ((size_t)b * N_SAMP + q.w) * 3;
    const float w0 = bw[0];
    const float w1 = bw[1];
    const float w2 = bw[2];

    const float* xb = xf + (size_t)b * N_VERTS * CC;
    const f32x4 f0 = *(const f32x4*)(xb + (size_t)q.x * CC + c0);
    const f32x4 f1 = *(const f32x4*)(xb + (size_t)q.y * CC + c0);
    const f32x4 f2 = *(const f32x4*)(xb + (size_t)q.z * CC + c0);
    const f32x4 fx = *(const f32x4*)(xb + (size_t)v   * CC + c0);

    f32x4 r;
    r.x = fmaf(w0, f0.x, fmaf(w1, f1.x, fmaf(w2, f2.x, -fx.x)));
    r.y = fmaf(w0, f0.y, fmaf(w1, f1.y, fmaf(w2, f2.y, -fx.y)));
    r.z = fmaf(w0, f0.z, fmaf(w1, f1.z, fmaf(w2, f2.z, -fx.z)));
    r.w = fmaf(w0, f0.w, fmaf(w1, f1.w, fmaf(w2, f2.w, -fx.w)));

    f32x4* dst = (f32x4*)(out + ((((size_t)b * N_VERTS + v) * CUT_NUM + k) * CC + c0));
    __builtin_nontemporal_store(r, dst);
}

// ---------------------------------------------------------------------------
// Fallback: round-4 fused single kernel (used only if d_ws is too small).
// ---------------------------------------------------------------------------
__global__ __launch_bounds__(256) void fused_disk_features(
    const float* __restrict__ xf,
    const float* __restrict__ Bw,
    const int*   __restrict__ xg,
    const int*   __restrict__ Fc,
    const int*   __restrict__ Iv,
    float*       __restrict__ out)
{
    const int v    = blockIdx.x;
    const int b    = blockIdx.y;
    const int t    = threadIdx.x;
    const int k    = t >> 5;
    const int lane = t & 31;
    const int c0   = lane * 4;

    const int s   = xg[v * CUT_NUM + k];
    const int fid = Iv[s];
    const int v0  = Fc[fid * 3 + 0];
    const int v1  = Fc[fid * 3 + 1];
    const int v2  = Fc[fid * 3 + 2];

    const float* bw = Bw + ((size_t)b * N_SAMP + s) * 3;
    const float w0 = bw[0];
    const float w1 = bw[1];
    const float w2 = bw[2];

    const float* xb = xf + (size_t)b * N_VERTS * CC;
    const f32x4 f0 = *(const f32x4*)(xb + (size_t)v0 * CC + c0);
    const f32x4 f1 = *(const f32x4*)(xb + (size_t)v1 * CC + c0);
    const f32x4 f2 = *(const f32x4*)(xb + (size_t)v2 * CC + c0);
    const f32x4 fx = *(const f32x4*)(xb + (size_t)v  * CC + c0);

    f32x4 r;
    r.x = fmaf(w0, f0.x, fmaf(w1, f1.x, fmaf(w2, f2.x, -fx.x)));
    r.y = fmaf(w0, f0.y, fmaf(w1, f1.y, fmaf(w2, f2.y, -fx.y)));
    r.z = fmaf(w0, f0.z, fmaf(w1, f1.z, fmaf(w2, f2.z, -fx.z)));
    r.w = fmaf(w0, f0.w, fmaf(w1, f1.w, fmaf(w2, f2.w, -fx.w)));

    f32x4* dst = (f32x4*)(out + ((((size_t)b * N_VERTS + v) * CUT_NUM + k) * CC + c0));
    __builtin_nontemporal_store(r, dst);
}

extern "C" void kernel_launch(void* const* d_in, const int* in_sizes, int n_in,
                              void* d_out, int out_size, void* d_ws, size_t ws_size,
                              hipStream_t stream) {
    const float* xf = (const float*)d_in[0];   // x_features (4,10000,128)
    const float* Bw = (const float*)d_in[1];   // B          (4,80000,3)
    const int*   xg = (const int*)  d_in[2];   // x_graph    (10000,8)
    const int*   Fc = (const int*)  d_in[3];   // F          (20000,3)
    const int*   Iv = (const int*)  d_in[4];   // I          (80000,)
    float*       out = (float*)d_out;          // (4,10000,8,128)

    const size_t quad_bytes = (size_t)N_VERTS * CUT_NUM * sizeof(i32x4);
    if (ws_size >= quad_bytes) {
        i32x4* quad = (i32x4*)d_ws;
        const int n_e = N_VERTS * CUT_NUM;
        idx_prep<<<(n_e + 255) / 256, 256, 0, stream>>>(xg, Fc, Iv, quad);
        dim3 grid(N_VERTS, BATCH);
        disk_features_main<<<grid, 256, 0, stream>>>(xf, Bw, quad, out);
    } else {
        dim3 grid(N_VERTS, BATCH);
        fused_disk_features<<<grid, 256, 0, stream>>>(xf, Bw, xg, Fc, Iv, out);
    }
}

// Round 7
// 59.167 us; speedup vs baseline: 1.5917x; 1.1113x over previous
//
#include <hip/hip_runtime.h>

// Problem constants (from reference)
#define BATCH   4
#define N_VERTS 10000
#define N_FACES 20000
#define CUT_NUM 8
#define N_SAMP  80000
#define CC      128

typedef float          f32x4 __attribute__((ext_vector_type(4)));
typedef int            i32x4 __attribute__((ext_vector_type(4)));
typedef unsigned short u16x4 __attribute__((ext_vector_type(4)));
typedef unsigned short u16x8 __attribute__((ext_vector_type(8)));

#define XB16_BYTES ((size_t)BATCH * N_VERTS * CC * 2)          // 10.24 MB
#define QUAD_BYTES ((size_t)N_VERTS * CUT_NUM * sizeof(i32x4)) // 1.28 MB

__device__ inline float bf16_to_f32(unsigned short u) {
    return __uint_as_float((unsigned)u << 16);
}

__device__ inline f32x4 bf4_to_f32(u16x4 u) {
    f32x4 r;
    r.x = bf16_to_f32(u.x);
    r.y = bf16_to_f32(u.y);
    r.z = bf16_to_f32(u.z);
    r.w = bf16_to_f32(u.w);
    return r;
}

// round-to-nearest-even f32 -> bf16
__device__ inline unsigned short f32_to_bf16(float f) {
    unsigned u = __float_as_uint(f);
    unsigned rounding = 0x7fffu + ((u >> 16) & 1u);
    return (unsigned short)((u + rounding) >> 16);
}

// ---------------------------------------------------------------------------
// Kernel A: convert x_features (f32) -> bf16 table in d_ws.
// 5.12M elements; each thread converts 8 (read 32B, write 16B).
// ---------------------------------------------------------------------------
__global__ __launch_bounds__(256) void to_bf16_kernel(
    const float* __restrict__ xf, unsigned short* __restrict__ x16)
{
    const size_t i = ((size_t)blockIdx.x * 256 + threadIdx.x) * 8;
    if (i >= (size_t)BATCH * N_VERTS * CC) return;
    const f32x4 a = *(const f32x4*)(xf + i);
    const f32x4 b = *(const f32x4*)(xf + i + 4);
    u16x8 o;
    o.s0 = f32_to_bf16(a.x); o.s1 = f32_to_bf16(a.y);
    o.s2 = f32_to_bf16(a.z); o.s3 = f32_to_bf16(a.w);
    o.s4 = f32_to_bf16(b.x); o.s5 = f32_to_bf16(b.y);
    o.s6 = f32_to_bf16(b.z); o.s7 = f32_to_bf16(b.w);
    *(u16x8*)(x16 + i) = o;
}

// ---------------------------------------------------------------------------
// Kernel B: resolve the batch-independent index chain once per (v,k).
//   quad[e] = { F[I[s]][0], F[I[s]][1], F[I[s]][2], s }  where s = xg[e]
// ---------------------------------------------------------------------------
__global__ __launch_bounds__(256) void idx_prep(
    const int* __restrict__ xg,
    const int* __restrict__ Fc,
    const int* __restrict__ Iv,
    i32x4*     __restrict__ quad)
{
    const int e = blockIdx.x * 256 + threadIdx.x;
    if (e >= N_VERTS * CUT_NUM) return;
    const int s   = xg[e];
    const int fid = Iv[s];
    i32x4 q;
    q.x = Fc[fid * 3 + 0];
    q.y = Fc[fid * 3 + 1];
    q.z = Fc[fid * 3 + 2];
    q.w = s;
    quad[e] = q;
}

// ---------------------------------------------------------------------------
// Kernel C: main. One block per (v,b). Gathers feature rows from the
// L2-resident bf16 table (256B/row, 8B/lane); subtrahend row stays f32.
// ---------------------------------------------------------------------------
__global__ __launch_bounds__(256) void disk_features_main(
    const float*          __restrict__ xf,   // [BATCH][N_VERTS][CC] f32
    const unsigned short* __restrict__ x16,  // [BATCH][N_VERTS][CC] bf16
    const float*          __restrict__ Bw,   // [BATCH][N_SAMP][3]
    const i32x4*          __restrict__ quad, // [N_VERTS*CUT_NUM]
    float*                __restrict__ out)  // [BATCH][N_VERTS][CUT_NUM][CC]
{
    const int v    = blockIdx.x;
    const int b    = blockIdx.y;
    const int t    = threadIdx.x;
    const int k    = t >> 5;        // 0..7
    const int lane = t & 31;        // 0..31
    const int c0   = lane * 4;

    const i32x4 q = quad[v * CUT_NUM + k];

    const float* bw = Bw + ((size_t)b * N_SAMP + q.w) * 3;
    const float w0 = bw[0];
    const float w1 = bw[1];
    const float w2 = bw[2];

    const unsigned short* xb = x16 + (size_t)b * N_VERTS * CC;
    const f32x4 f0 = bf4_to_f32(*(const u16x4*)(xb + (size_t)q.x * CC + c0));
    const f32x4 f1 = bf4_to_f32(*(const u16x4*)(xb + (size_t)q.y * CC + c0));
    const f32x4 f2 = bf4_to_f32(*(const u16x4*)(xb + (size_t)q.z * CC + c0));
    const f32x4 fx = *(const f32x4*)(xf + (size_t)b * N_VERTS * CC + (size_t)v * CC + c0);

    f32x4 r;
    r.x = fmaf(w0, f0.x, fmaf(w1, f1.x, fmaf(w2, f2.x, -fx.x)));
    r.y = fmaf(w0, f0.y, fmaf(w1, f1.y, fmaf(w2, f2.y, -fx.y)));
    r.z = fmaf(w0, f0.z, fmaf(w1, f1.z, fmaf(w2, f2.z, -fx.z)));
    r.w = fmaf(w0, f0.w, fmaf(w1, f1.w, fmaf(w2, f2.w, -fx.w)));

    f32x4* dst = (f32x4*)(out + ((((size_t)b * N_VERTS + v) * CUT_NUM + k) * CC + c0));
    __builtin_nontemporal_store(r, dst);
}

// ---------------------------------------------------------------------------
// Fallback path (f32 gathers, quad precompute) — round-6 kernel.
// ---------------------------------------------------------------------------
__global__ __launch_bounds__(256) void disk_features_f32(
    const float* __restrict__ xf,
    const float* __restrict__ Bw,
    const i32x4* __restrict__ quad,
    float*       __restrict__ out)
{
    const int v    = blockIdx.x;
    const int b    = blockIdx.y;
    const int t    = threadIdx.x;
    const int k    = t >> 5;
    const int lane = t & 31;
    const int c0   = lane * 4;

    const i32x4 q = quad[v * CUT_NUM + k];

    const float* bw = Bw + ((size_t)b * N_SAMP + q.w) * 3;
    const float w0 = bw[0];
    const float w1 = bw[1];
    const float w2 = bw[2];

    const float* xb = xf + (size_t)b * N_VERTS * CC;
    const f32x4 f0 = *(const f32x4*)(xb + (size_t)q.x * CC + c0);
    const f32x4 f1 = *(const f32x4*)(xb + (size_t)q.y * CC + c0);
    const f32x4 f2 = *(const f32x4*)(xb + (size_t)q.z * CC + c0);
    const f32x4 fx = *(const f32x4*)(xb + (size_t)v   * CC + c0);

    f32x4 r;
    r.x = fmaf(w0, f0.x, fmaf(w1, f1.x, fmaf(w2, f2.x, -fx.x)));
    r.y = fmaf(w0, f0.y, fmaf(w1, f1.y, fmaf(w2, f2.y, -fx.y)));
    r.z = fmaf(w0, f0.z, fmaf(w1, f1.z, fmaf(w2, f2.z, -fx.z)));
    r.w = fmaf(w0, f0.w, fmaf(w1, f1.w, fmaf(w2, f2.w, -fx.w)));

    f32x4* dst = (f32x4*)(out + ((((size_t)b * N_VERTS + v) * CUT_NUM + k) * CC + c0));
    __builtin_nontemporal_store(r, dst);
}

__global__ __launch_bounds__(256) void fused_disk_features(
    const float* __restrict__ xf,
    const float* __restrict__ Bw,
    const int*   __restrict__ xg,
    const int*   __restrict__ Fc,
    const int*   __restrict__ Iv,
    float*       __restrict__ out)
{
    const int v    = blockIdx.x;
    const int b    = blockIdx.y;
    const int t    = threadIdx.x;
    const int k    = t >> 5;
    const int lane = t & 31;
    const int c0   = lane * 4;

    const int s   = xg[v * CUT_NUM + k];
    const int fid = Iv[s];
    const int v0  = Fc[fid * 3 + 0];
    const int v1  = Fc[fid * 3 + 1];
    const int v2  = Fc[fid * 3 + 2];

    const float* bw = Bw + ((size_t)b * N_SAMP + s) * 3;
    const float w0 = bw[0];
    const float w1 = bw[1];
    const float w2 = bw[2];

    const float* xb = xf + (size_t)b * N_VERTS * CC;
    const f32x4 f0 = *(const f32x4*)(xb + (size_t)v0 * CC + c0);
    const f32x4 f1 = *(const f32x4*)(xb + (size_t)v1 * CC + c0);
    const f32x4 f2 = *(const f32x4*)(xb + (size_t)v2 * CC + c0);
    const f32x4 fx = *(const f32x4*)(xb + (size_t)v  * CC + c0);

    f32x4 r;
    r.x = fmaf(w0, f0.x, fmaf(w1, f1.x, fmaf(w2, f2.x, -fx.x)));
    r.y = fmaf(w0, f0.y, fmaf(w1, f1.y, fmaf(w2, f2.y, -fx.y)));
    r.z = fmaf(w0, f0.z, fmaf(w1, f1.z, fmaf(w2, f2.z, -fx.z)));
    r.w = fmaf(w0, f0.w, fmaf(w1, f1.w, fmaf(w2, f2.w, -fx.w)));

    f32x4* dst = (f32x4*)(out + ((((size_t)b * N_VERTS + v) * CUT_NUM + k) * CC + c0));
    __builtin_nontemporal_store(r, dst);
}

extern "C" void kernel_launch(void* const* d_in, const int* in_sizes, int n_in,
                              void* d_out, int out_size, void* d_ws, size_t ws_size,
                              hipStream_t stream) {
    const float* xf = (const float*)d_in[0];   // x_features (4,10000,128)
    const float* Bw = (const float*)d_in[1];   // B          (4,80000,3)
    const int*   xg = (const int*)  d_in[2];   // x_graph    (10000,8)
    const int*   Fc = (const int*)  d_in[3];   // F          (20000,3)
    const int*   Iv = (const int*)  d_in[4];   // I          (80000,)
    float*       out = (float*)d_out;          // (4,10000,8,128)

    const int n_e = N_VERTS * CUT_NUM;
    dim3 grid(N_VERTS, BATCH);

    if (ws_size >= XB16_BYTES + QUAD_BYTES) {
        unsigned short* x16  = (unsigned short*)d_ws;
        i32x4*          quad = (i32x4*)((char*)d_ws + XB16_BYTES);
        const size_t n_conv = (size_t)BATCH * N_VERTS * CC / 8;   // 640K threads
        to_bf16_kernel<<<(unsigned)((n_conv + 255) / 256), 256, 0, stream>>>(xf, x16);
        idx_prep<<<(n_e + 255) / 256, 256, 0, stream>>>(xg, Fc, Iv, quad);
        disk_features_main<<<grid, 256, 0, stream>>>(xf, x16, Bw, quad, out);
    } else if (ws_size >= QUAD_BYTES) {
        i32x4* quad = (i32x4*)d_ws;
        idx_prep<<<(n_e + 255) / 256, 256, 0, stream>>>(xg, Fc, Iv, quad);
        disk_features_f32<<<grid, 256, 0, stream>>>(xf, Bw, quad, out);
    } else {
        fused_disk_features<<<grid, 256, 0, stream>>>(xf, Bw, xg, Fc, Iv, out);
    }
}

// Round 10
// 55.613 us; speedup vs baseline: 1.6934x; 1.0639x over previous
//
#include <hip/hip_runtime.h>

// Problem constants (from reference)
#define BATCH   4
#define N_VERTS 10000
#define N_FACES 20000
#define CUT_NUM 8
#define N_SAMP  80000
#define CC      128
#define NXCD    8

typedef float          f32x4 __attribute__((ext_vector_type(4)));
typedef int            i32x4 __attribute__((ext_vector_type(4)));
typedef unsigned short u16x4 __attribute__((ext_vector_type(4)));
typedef unsigned short u16x8 __attribute__((ext_vector_type(8)));

#define XB16_BYTES ((size_t)BATCH * N_VERTS * CC * 2)          // 10.24 MB
#define QUAD_BYTES ((size_t)N_VERTS * CUT_NUM * sizeof(i32x4)) // 1.28 MB

__device__ inline float bf16_to_f32(unsigned short u) {
    return __uint_as_float((unsigned)u << 16);
}

__device__ inline f32x4 bf4_to_f32(u16x4 u) {
    f32x4 r;
    r.x = bf16_to_f32(u.x);
    r.y = bf16_to_f32(u.y);
    r.z = bf16_to_f32(u.z);
    r.w = bf16_to_f32(u.w);
    return r;
}

// round-to-nearest-even f32 -> bf16
__device__ inline unsigned short f32_to_bf16(float f) {
    unsigned u = __float_as_uint(f);
    unsigned rounding = 0x7fffu + ((u >> 16) & 1u);
    return (unsigned short)((u + rounding) >> 16);
}

// ---------------------------------------------------------------------------
// Kernel A: convert x_features (f32) -> bf16 table in d_ws.
// ---------------------------------------------------------------------------
__global__ __launch_bounds__(256) void to_bf16_kernel(
    const float* __restrict__ xf, unsigned short* __restrict__ x16)
{
    const size_t i = ((size_t)blockIdx.x * 256 + threadIdx.x) * 8;
    if (i >= (size_t)BATCH * N_VERTS * CC) return;
    const f32x4 a = *(const f32x4*)(xf + i);
    const f32x4 b = *(const f32x4*)(xf + i + 4);
    u16x8 o;
    o.s0 = f32_to_bf16(a.x); o.s1 = f32_to_bf16(a.y);
    o.s2 = f32_to_bf16(a.z); o.s3 = f32_to_bf16(a.w);
    o.s4 = f32_to_bf16(b.x); o.s5 = f32_to_bf16(b.y);
    o.s6 = f32_to_bf16(b.z); o.s7 = f32_to_bf16(b.w);
    *(u16x8*)(x16 + i) = o;
}

// ---------------------------------------------------------------------------
// Kernel B: resolve the batch-independent index chain once per (v,k).
// ---------------------------------------------------------------------------
__global__ __launch_bounds__(256) void idx_prep(
    const int* __restrict__ xg,
    const int* __restrict__ Fc,
    const int* __restrict__ Iv,
    i32x4*     __restrict__ quad)
{
    const int e = blockIdx.x * 256 + threadIdx.x;
    if (e >= N_VERTS * CUT_NUM) return;
    const int s   = xg[e];
    const int fid = Iv[s];
    i32x4 q;
    q.x = Fc[fid * 3 + 0];
    q.y = Fc[fid * 3 + 1];
    q.z = Fc[fid * 3 + 2];
    q.w = s;
    quad[e] = q;
}

// ---------------------------------------------------------------------------
// Kernel C: main. 1D grid of 40000 blocks, XCD-swizzled so each XCD handles
// exactly ONE batch plane (2 XCDs per b):
//   xcd = L & 7 ; b = xcd >> 1 ; v = (L >> 3) + (xcd & 1) * 5000
// Per-XCD gather working set = one bf16 plane (2.56 MB) -> L2-resident.
// ---------------------------------------------------------------------------
__global__ __launch_bounds__(256) void disk_features_main(
    const float*          __restrict__ xf,   // [BATCH][N_VERTS][CC] f32
    const unsigned short* __restrict__ x16,  // [BATCH][N_VERTS][CC] bf16
    const float*          __restrict__ Bw,   // [BATCH][N_SAMP][3]
    const i32x4*          __restrict__ quad, // [N_VERTS*CUT_NUM]
    float*                __restrict__ out)  // [BATCH][N_VERTS][CUT_NUM][CC]
{
    const int L    = blockIdx.x;
    const int xcd  = L & (NXCD - 1);
    const int b    = xcd >> 1;                          // 0..3
    const int v    = (L >> 3) + (xcd & 1) * (N_VERTS / 2);
    const int t    = threadIdx.x;
    const int k    = t >> 5;        // 0..7
    const int lane = t & 31;        // 0..31
    const int c0   = lane * 4;

    const i32x4 q = quad[v * CUT_NUM + k];

    const float* bw = Bw + ((size_t)b * N_SAMP + q.w) * 3;
    const float w0 = bw[0];
    const float w1 = bw[1];
    const float w2 = bw[2];

    const unsigned short* xb = x16 + (size_t)b * N_VERTS * CC;
    const f32x4 f0 = bf4_to_f32(*(const u16x4*)(xb + (size_t)q.x * CC + c0));
    const f32x4 f1 = bf4_to_f32(*(const u16x4*)(xb + (size_t)q.y * CC + c0));
    const f32x4 f2 = bf4_to_f32(*(const u16x4*)(xb + (size_t)q.z * CC + c0));
    const f32x4 fx = *(const f32x4*)(xf + (size_t)b * N_VERTS * CC + (size_t)v * CC + c0);

    f32x4 r;
    r.x = fmaf(w0, f0.x, fmaf(w1, f1.x, fmaf(w2, f2.x, -fx.x)));
    r.y = fmaf(w0, f0.y, fmaf(w1, f1.y, fmaf(w2, f2.y, -fx.y)));
    r.z = fmaf(w0, f0.z, fmaf(w1, f1.z, fmaf(w2, f2.z, -fx.z)));
    r.w = fmaf(w0, f0.w, fmaf(w1, f1.w, fmaf(w2, f2.w, -fx.w)));

    f32x4* dst = (f32x4*)(out + ((((size_t)b * N_VERTS + v) * CUT_NUM + k) * CC + c0));
    __builtin_nontemporal_store(r, dst);
}

// ---------------------------------------------------------------------------
// Fallback paths.
// ---------------------------------------------------------------------------
__global__ __launch_bounds__(256) void disk_features_f32(
    const float* __restrict__ xf,
    const float* __restrict__ Bw,
    const i32x4* __restrict__ quad,
    float*       __restrict__ out)
{
    const int v    = blockIdx.x;
    const int b    = blockIdx.y;
    const int t    = threadIdx.x;
    const int k    = t >> 5;
    const int lane = t & 31;
    const int c0   = lane * 4;

    const i32x4 q = quad[v * CUT_NUM + k];

    const float* bw = Bw + ((size_t)b * N_SAMP + q.w) * 3;
    const float w0 = bw[0];
    const float w1 = bw[1];
    const float w2 = bw[2];

    const float* xb = xf + (size_t)b * N_VERTS * CC;
    const f32x4 f0 = *(const f32x4*)(xb + (size_t)q.x * CC + c0);
    const f32x4 f1 = *(const f32x4*)(xb + (size_t)q.y * CC + c0);
    const f32x4 f2 = *(const f32x4*)(xb + (size_t)q.z * CC + c0);
    const f32x4 fx = *(const f32x4*)(xb + (size_t)v   * CC + c0);

    f32x4 r;
    r.x = fmaf(w0, f0.x, fmaf(w1, f1.x, fmaf(w2, f2.x, -fx.x)));
    r.y = fmaf(w0, f0.y, fmaf(w1, f1.y, fmaf(w2, f2.y, -fx.y)));
    r.z = fmaf(w0, f0.z, fmaf(w1, f1.z, fmaf(w2, f2.z, -fx.z)));
    r.w = fmaf(w0, f0.w, fmaf(w1, f1.w, fmaf(w2, f2.w, -fx.w)));

    f32x4* dst = (f32x4*)(out + ((((size_t)b * N_VERTS + v) * CUT_NUM + k) * CC + c0));
    __builtin_nontemporal_store(r, dst);
}

__global__ __launch_bounds__(256) void fused_disk_features(
    const float* __restrict__ xf,
    const float* __restrict__ Bw,
    const int*   __restrict__ xg,
    const int*   __restrict__ Fc,
    const int*   __restrict__ Iv,
    float*       __restrict__ out)
{
    const int v    = blockIdx.x;
    const int b    = blockIdx.y;
    const int t    = threadIdx.x;
    const int k    = t >> 5;
    const int lane = t & 31;
    const int c0   = lane * 4;

    const int s   = xg[v * CUT_NUM + k];
    const int fid = Iv[s];
    const int v0  = Fc[fid * 3 + 0];
    const int v1  = Fc[fid * 3 + 1];
    const int v2  = Fc[fid * 3 + 2];

    const float* bw = Bw + ((size_t)b * N_SAMP + s) * 3;
    const float w0 = bw[0];
    const float w1 = bw[1];
    const float w2 = bw[2];

    const float* xb = xf + (size_t)b * N_VERTS * CC;
    const f32x4 f0 = *(const f32x4*)(xb + (size_t)v0 * CC + c0);
    const f32x4 f1 = *(const f32x4*)(xb + (size_t)v1 * CC + c0);
    const f32x4 f2 = *(const f32x4*)(xb + (size_t)v2 * CC + c0);
    const f32x4 fx = *(const f32x4*)(xb + (size_t)v  * CC + c0);

    f32x4 r;
    r.x = fmaf(w0, f0.x, fmaf(w1, f1.x, fmaf(w2, f2.x, -fx.x)));
    r.y = fmaf(w0, f0.y, fmaf(w1, f1.y, fmaf(w2, f2.y, -fx.y)));
    r.z = fmaf(w0, f0.z, fmaf(w1, f1.z, fmaf(w2, f2.z, -fx.z)));
    r.w = fmaf(w0, f0.w, fmaf(w1, f1.w, fmaf(w2, f2.w, -fx.w)));

    f32x4* dst = (f32x4*)(out + ((((size_t)b * N_VERTS + v) * CUT_NUM + k) * CC + c0));
    __builtin_nontemporal_store(r, dst);
}

extern "C" void kernel_launch(void* const* d_in, const int* in_sizes, int n_in,
                              void* d_out, int out_size, void* d_ws, size_t ws_size,
                              hipStream_t stream) {
    const float* xf = (const float*)d_in[0];   // x_features (4,10000,128)
    const float* Bw = (const float*)d_in[1];   // B          (4,80000,3)
    const int*   xg = (const int*)  d_in[2];   // x_graph    (10000,8)
    const int*   Fc = (const int*)  d_in[3];   // F          (20000,3)
    const int*   Iv = (const int*)  d_in[4];   // I          (80000,)
    float*       out = (float*)d_out;          // (4,10000,8,128)

    const int n_e = N_VERTS * CUT_NUM;

    if (ws_size >= XB16_BYTES + QUAD_BYTES) {
        unsigned short* x16  = (unsigned short*)d_ws;
        i32x4*          quad = (i32x4*)((char*)d_ws + XB16_BYTES);
        const size_t n_conv = (size_t)BATCH * N_VERTS * CC / 8;   // 640K threads
        to_bf16_kernel<<<(unsigned)((n_conv + 255) / 256), 256, 0, stream>>>(xf, x16);
        idx_prep<<<(n_e + 255) / 256, 256, 0, stream>>>(xg, Fc, Iv, quad);
        disk_features_main<<<N_VERTS * BATCH, 256, 0, stream>>>(xf, x16, Bw, quad, out);
    } else if (ws_size >= QUAD_BYTES) {
        i32x4* quad = (i32x4*)d_ws;
        idx_prep<<<(n_e + 255) / 256, 256, 0, stream>>>(xg, Fc, Iv, quad);
        dim3 grid(N_VERTS, BATCH);
        disk_features_f32<<<grid, 256, 0, stream>>>(xf, Bw, quad, out);
    } else {
        dim3 grid(N_VERTS, BATCH);
        fused_disk_features<<<grid, 256, 0, stream>>>(xf, Bw, xg, Fc, Iv, out);
    }
}

// Round 11
// 47.356 us; speedup vs baseline: 1.9887x; 1.1744x over previous
//
#include <hip/hip_runtime.h>

// Problem constants (from reference)
#define BATCH   4
#define N_VERTS 10000
#define N_FACES 20000
#define CUT_NUM 8
#define N_SAMP  80000
#define CC      128
#define NXCD    8

typedef float          f32x4 __attribute__((ext_vector_type(4)));
typedef int            i32x4 __attribute__((ext_vector_type(4)));
typedef unsigned short u16x4 __attribute__((ext_vector_type(4)));
typedef unsigned short u16x8 __attribute__((ext_vector_type(8)));

#define XB16_BYTES ((size_t)BATCH * N_VERTS * CC * 2)          // 10.24 MB
#define QUAD_BYTES ((size_t)N_VERTS * CUT_NUM * sizeof(i32x4)) // 1.28 MB
#define CONV_BLOCKS 2500   // 2500*256*8 == BATCH*N_VERTS*CC exactly
#define IDX_BLOCKS  313    // ceil(80000/256)

__device__ inline float bf16_to_f32(unsigned short u) {
    return __uint_as_float((unsigned)u << 16);
}

// round-to-nearest-even f32 -> bf16
__device__ inline unsigned short f32_to_bf16(float f) {
    unsigned u = __float_as_uint(f);
    unsigned rounding = 0x7fffu + ((u >> 16) & 1u);
    return (unsigned short)((u + rounding) >> 16);
}

// ---------------------------------------------------------------------------
// Fused prep: blocks [0,CONV_BLOCKS) convert x_features f32->bf16;
// blocks [CONV_BLOCKS, CONV_BLOCKS+IDX_BLOCKS) resolve the index chain:
//   quad[e] = { F[I[s]][0], F[I[s]][1], F[I[s]][2], s },  s = xg[e]
// ---------------------------------------------------------------------------
__global__ __launch_bounds__(256) void prep_kernel(
    const float* __restrict__ xf,
    const int*   __restrict__ xg,
    const int*   __restrict__ Fc,
    const int*   __restrict__ Iv,
    unsigned short* __restrict__ x16,
    i32x4*          __restrict__ quad)
{
    const int bid = blockIdx.x;
    if (bid < CONV_BLOCKS) {
        const size_t i = ((size_t)bid * 256 + threadIdx.x) * 8;
        const f32x4 a = *(const f32x4*)(xf + i);
        const f32x4 b = *(const f32x4*)(xf + i + 4);
        u16x8 o;
        o.s0 = f32_to_bf16(a.x); o.s1 = f32_to_bf16(a.y);
        o.s2 = f32_to_bf16(a.z); o.s3 = f32_to_bf16(a.w);
        o.s4 = f32_to_bf16(b.x); o.s5 = f32_to_bf16(b.y);
        o.s6 = f32_to_bf16(b.z); o.s7 = f32_to_bf16(b.w);
        *(u16x8*)(x16 + i) = o;
    } else {
        const int e = (bid - CONV_BLOCKS) * 256 + threadIdx.x;
        if (e < N_VERTS * CUT_NUM) {
            const int s   = xg[e];
            const int fid = Iv[s];
            i32x4 q;
            q.x = Fc[fid * 3 + 0];
            q.y = Fc[fid * 3 + 1];
            q.z = Fc[fid * 3 + 2];
            q.w = s;
            quad[e] = q;
        }
    }
}

// ---------------------------------------------------------------------------
// Main: 20000 blocks (2 vertices each), XCD-swizzled so each XCD handles one
// batch plane (2 XCDs per b). 16 lanes per output row, 16B/lane bf16 gathers.
//   xcd = L & 7 ; b = xcd >> 1 ; vp = (L>>3) + (xcd&1)*2500 ; v = vp*2 + (g>>3)
// ---------------------------------------------------------------------------
__global__ __launch_bounds__(256) void disk_features_main(
    const unsigned short* __restrict__ x16,  // [BATCH][N_VERTS][CC] bf16
    const float*          __restrict__ Bw,   // [BATCH][N_SAMP][3]
    const i32x4*          __restrict__ quad, // [N_VERTS*CUT_NUM]
    float*                __restrict__ out)  // [BATCH][N_VERTS][CUT_NUM][CC]
{
    const int L    = blockIdx.x;
    const int xcd  = L & (NXCD - 1);
    const int b    = xcd >> 1;                             // 0..3
    const int vp   = (L >> 3) + (xcd & 1) * (N_VERTS / 4); // 0..4999
    const int t    = threadIdx.x;
    const int g    = t >> 4;          // 0..15 (row group)
    const int lane = t & 15;          // 0..15
    const int k    = g & 7;
    const int v    = vp * 2 + (g >> 3);
    const int c0   = lane * 8;        // 8 bf16 channels per lane

    const i32x4 q = quad[v * CUT_NUM + k];

    const float* bw = Bw + ((size_t)b * N_SAMP + q.w) * 3;
    const float w0 = bw[0];
    const float w1 = bw[1];
    const float w2 = bw[2];

    const unsigned short* xb = x16 + (size_t)b * N_VERTS * CC;
    const u16x8 a0 = *(const u16x8*)(xb + (size_t)q.x * CC + c0);
    const u16x8 a1 = *(const u16x8*)(xb + (size_t)q.y * CC + c0);
    const u16x8 a2 = *(const u16x8*)(xb + (size_t)q.z * CC + c0);
    const u16x8 ax = *(const u16x8*)(xb + (size_t)v   * CC + c0);

    f32x4 r0, r1;
    #pragma unroll
    for (int j = 0; j < 4; ++j) {
        const float f0 = bf16_to_f32(a0[j]);
        const float f1 = bf16_to_f32(a1[j]);
        const float f2 = bf16_to_f32(a2[j]);
        const float fx = bf16_to_f32(ax[j]);
        r0[j] = fmaf(w0, f0, fmaf(w1, f1, fmaf(w2, f2, -fx)));
    }
    #pragma unroll
    for (int j = 0; j < 4; ++j) {
        const float f0 = bf16_to_f32(a0[j + 4]);
        const float f1 = bf16_to_f32(a1[j + 4]);
        const float f2 = bf16_to_f32(a2[j + 4]);
        const float fx = bf16_to_f32(ax[j + 4]);
        r1[j] = fmaf(w0, f0, fmaf(w1, f1, fmaf(w2, f2, -fx)));
    }

    float* dst = out + ((((size_t)b * N_VERTS + v) * CUT_NUM + k) * CC + c0);
    __builtin_nontemporal_store(r0, (f32x4*)dst);
    __builtin_nontemporal_store(r1, (f32x4*)(dst + 4));
}

// ---------------------------------------------------------------------------
// Fallback paths (smaller ws).
// ---------------------------------------------------------------------------
__global__ __launch_bounds__(256) void idx_prep(
    const int* __restrict__ xg,
    const int* __restrict__ Fc,
    const int* __restrict__ Iv,
    i32x4*     __restrict__ quad)
{
    const int e = blockIdx.x * 256 + threadIdx.x;
    if (e >= N_VERTS * CUT_NUM) return;
    const int s   = xg[e];
    const int fid = Iv[s];
    i32x4 q;
    q.x = Fc[fid * 3 + 0];
    q.y = Fc[fid * 3 + 1];
    q.z = Fc[fid * 3 + 2];
    q.w = s;
    quad[e] = q;
}

__global__ __launch_bounds__(256) void disk_features_f32(
    const float* __restrict__ xf,
    const float* __restrict__ Bw,
    const i32x4* __restrict__ quad,
    float*       __restrict__ out)
{
    const int v    = blockIdx.x;
    const int b    = blockIdx.y;
    const int t    = threadIdx.x;
    const int k    = t >> 5;
    const int lane = t & 31;
    const int c0   = lane * 4;

    const i32x4 q = quad[v * CUT_NUM + k];

    const float* bw = Bw + ((size_t)b * N_SAMP + q.w) * 3;
    const float w0 = bw[0];
    const float w1 = bw[1];
    const float w2 = bw[2];

    const float* xb = xf + (size_t)b * N_VERTS * CC;
    const f32x4 f0 = *(const f32x4*)(xb + (size_t)q.x * CC + c0);
    const f32x4 f1 = *(const f32x4*)(xb + (size_t)q.y * CC + c0);
    const f32x4 f2 = *(const f32x4*)(xb + (size_t)q.z * CC + c0);
    const f32x4 fx = *(const f32x4*)(xb + (size_t)v   * CC + c0);

    f32x4 r;
    r.x = fmaf(w0, f0.x, fmaf(w1, f1.x, fmaf(w2, f2.x, -fx.x)));
    r.y = fmaf(w0, f0.y, fmaf(w1, f1.y, fmaf(w2, f2.y, -fx.y)));
    r.z = fmaf(w0, f0.z, fmaf(w1, f1.z, fmaf(w2, f2.z, -fx.z)));
    r.w = fmaf(w0, f0.w, fmaf(w1, f1.w, fmaf(w2, f2.w, -fx.w)));

    f32x4* dst = (f32x4*)(out + ((((size_t)b * N_VERTS + v) * CUT_NUM + k) * CC + c0));
    __builtin_nontemporal_store(r, dst);
}

__global__ __launch_bounds__(256) void fused_disk_features(
    const float* __restrict__ xf,
    const float* __restrict__ Bw,
    const int*   __restrict__ xg,
    const int*   __restrict__ Fc,
    const int*   __restrict__ Iv,
    float*       __restrict__ out)
{
    const int v    = blockIdx.x;
    const int b    = blockIdx.y;
    const int t    = threadIdx.x;
    const int k    = t >> 5;
    const int lane = t & 31;
    const int c0   = lane * 4;

    const int s   = xg[v * CUT_NUM + k];
    const int fid = Iv[s];
    const int v0  = Fc[fid * 3 + 0];
    const int v1  = Fc[fid * 3 + 1];
    const int v2  = Fc[fid * 3 + 2];

    const float* bw = Bw + ((size_t)b * N_SAMP + s) * 3;
    const float w0 = bw[0];
    const float w1 = bw[1];
    const float w2 = bw[2];

    const float* xb = xf + (size_t)b * N_VERTS * CC;
    const f32x4 f0 = *(const f32x4*)(xb + (size_t)v0 * CC + c0);
    const f32x4 f1 = *(const f32x4*)(xb + (size_t)v1 * CC + c0);
    const f32x4 f2 = *(const f32x4*)(xb + (size_t)v2 * CC + c0);
    const f32x4 fx = *(const f32x4*)(xb + (size_t)v  * CC + c0);

    f32x4 r;
    r.x = fmaf(w0, f0.x, fmaf(w1, f1.x, fmaf(w2, f2.x, -fx.x)));
    r.y = fmaf(w0, f0.y, fmaf(w1, f1.y, fmaf(w2, f2.y, -fx.y)));
    r.z = fmaf(w0, f0.z, fmaf(w1, f1.z, fmaf(w2, f2.z, -fx.z)));
    r.w = fmaf(w0, f0.w, fmaf(w1, f1.w, fmaf(w2, f2.w, -fx.w)));

    f32x4* dst = (f32x4*)(out + ((((size_t)b * N_VERTS + v) * CUT_NUM + k) * CC + c0));
    __builtin_nontemporal_store(r, dst);
}

extern "C" void kernel_launch(void* const* d_in, const int* in_sizes, int n_in,
                              void* d_out, int out_size, void* d_ws, size_t ws_size,
                              hipStream_t stream) {
    const float* xf = (const float*)d_in[0];   // x_features (4,10000,128)
    const float* Bw = (const float*)d_in[1];   // B          (4,80000,3)
    const int*   xg = (const int*)  d_in[2];   // x_graph    (10000,8)
    const int*   Fc = (const int*)  d_in[3];   // F          (20000,3)
    const int*   Iv = (const int*)  d_in[4];   // I          (80000,)
    float*       out = (float*)d_out;          // (4,10000,8,128)

    const int n_e = N_VERTS * CUT_NUM;

    if (ws_size >= XB16_BYTES + QUAD_BYTES) {
        unsigned short* x16  = (unsigned short*)d_ws;
        i32x4*          quad = (i32x4*)((char*)d_ws + XB16_BYTES);
        prep_kernel<<<CONV_BLOCKS + IDX_BLOCKS, 256, 0, stream>>>(xf, xg, Fc, Iv, x16, quad);
        disk_features_main<<<N_VERTS * BATCH / 2, 256, 0, stream>>>(x16, Bw, quad, out);
    } else if (ws_size >= QUAD_BYTES) {
        i32x4* quad = (i32x4*)d_ws;
        idx_prep<<<(n_e + 255) / 256, 256, 0, stream>>>(xg, Fc, Iv, quad);
        dim3 grid(N_VERTS, BATCH);
        disk_features_f32<<<grid, 256, 0, stream>>>(xf, Bw, quad, out);
    } else {
        dim3 grid(N_VERTS, BATCH);
        fused_disk_features<<<grid, 256, 0, stream>>>(xf, Bw, xg, Fc, Iv, out);
    }
}